// Round 12
// baseline (63.532 us; speedup 1.0000x reference)
//
#include <hip/hip_runtime.h>
#include <hip/hip_bf16.h>

// out[e] = concat(h[i0], h[i1]) @ W + b, h = logmap0(x)
// Rewritten: y[n][0:4] = h[n]·W[0:128,:] + b   (b folded here)
//            y[n][4:8] = h[n]·W[128:256,:]
//            out[e][c] = y[i0][c] + y[i1][4+c]
//
// R12 = DIAGNOSTIC: node kernel body repeated 5x (idempotent, laundered
// pointer so the compiler can't hoist) to push its dispatch above the 39us
// harness fill dispatches and finally capture its rocprof counter row.
// dur_us this round is knowingly inflated by ~4x the node unit time.

#define DIM 128
#define NODE_REPEATS 5

typedef float f32x4 __attribute__((ext_vector_type(4)));
typedef int   i32x2 __attribute__((ext_vector_type(2)));

__global__ __launch_bounds__(256) void node_proj_kernel(
    const float* __restrict__ x, const float* __restrict__ W,
    const float* __restrict__ b, float* __restrict__ y, int n_nodes,
    int repeats)
{
    __shared__ float wp[1152];
    const int t = threadIdx.x;
    {
        const int r = t & 127, h = t >> 7;            // row, half
        const f32x4 wv = ((const f32x4*)W)[t];        // W[256][4], row t
        *(f32x4*)(wp + r * 8 + (r >> 2) * 4 + h * 4) = wv;
    }
    __syncthreads();

    const int lane = t & 63;
    const int li   = lane & 3;
    const int gid  = lane >> 2;
    const int wid  = blockIdx.x * (blockDim.x >> 6) + (t >> 6);
    const int n0   = wid * 32 + gid * 2;
    if (n0 >= n_nodes) return;
    const bool has1 = (n0 + 1) < n_nodes;
    const int  n1   = has1 ? (n0 + 1) : n0;
    const float* wl  = wp + li * 36;   // f(li*4) = li*32 + li*4

    for (int r = 0; r < repeats; ++r) {
        // Launder a zero offset so the compiler cannot prove the repeat
        // body loop-invariant (keeps loads/FMAs live each iteration).
        int zero = 0;
        asm volatile("" : "+v"(zero));
        const float* xr = x + zero;

        const f32x4* xp0 = (const f32x4*)(xr + (size_t)n0 * DIM + li * 4);
        const f32x4* xp1 = (const f32x4*)(xr + (size_t)n1 * DIM + li * 4);

        float acc0[9], acc1[9];
#pragma unroll
        for (int i = 0; i < 9; ++i) { acc0[i] = 0.f; acc1[i] = 0.f; }

#pragma unroll
        for (int j = 0; j < 8; ++j) {
            const f32x4 a4 = xp0[j * 4];
            const f32x4 b4 = xp1[j * 4];
#pragma unroll
            for (int k = 0; k < 4; ++k) {
                // d = j*16 + li*4 + k ; float-offset = li*36 + j*144 + k*8
                const f32x4 wa = *(const f32x4*)(wl + j * 144 + k * 8);
                const f32x4 wb = *(const f32x4*)(wl + j * 144 + k * 8 + 4);
                const float a = a4[k], bb = b4[k];
                acc0[0] += a * a;        acc1[0] += bb * bb;
                acc0[1] += a * wa[0];    acc1[1] += bb * wa[0];
                acc0[2] += a * wa[1];    acc1[2] += bb * wa[1];
                acc0[3] += a * wa[2];    acc1[3] += bb * wa[2];
                acc0[4] += a * wa[3];    acc1[4] += bb * wa[3];
                acc0[5] += a * wb[0];    acc1[5] += bb * wb[0];
                acc0[6] += a * wb[1];    acc1[6] += bb * wb[1];
                acc0[7] += a * wb[2];    acc1[7] += bb * wb[2];
                acc0[8] += a * wb[3];    acc1[8] += bb * wb[3];
            }
        }

#pragma unroll
        for (int i = 0; i < 9; ++i) {
            acc0[i] += __shfl_xor(acc0[i], 1, 64);
            acc0[i] += __shfl_xor(acc0[i], 2, 64);
            acc1[i] += __shfl_xor(acc1[i], 1, 64);
            acc1[i] += __shfl_xor(acc1[i], 2, 64);
        }

        const bool second = (li & 1);
        const bool nodeB  = (li >= 2);

        const float sq = nodeB ? acc1[0] : acc0[0];
        const float w0 = second ? (nodeB ? acc1[5] : acc0[5]) : (nodeB ? acc1[1] : acc0[1]);
        const float w1 = second ? (nodeB ? acc1[6] : acc0[6]) : (nodeB ? acc1[2] : acc0[2]);
        const float w2 = second ? (nodeB ? acc1[7] : acc0[7]) : (nodeB ? acc1[3] : acc0[3]);
        const float w3 = second ? (nodeB ? acc1[8] : acc0[8]) : (nodeB ? acc1[4] : acc0[4]);

        float norm = fmaxf(sqrtf(sq), 1e-15f);               // MIN_NORM
        const float aa  = fminf(norm, 1.0f - 1e-6f);         // ATANH_EPS clip
        const float art = 0.5f * log1pf(2.0f * aa / (1.0f - aa));  // artanh
        const float scale = art / norm;

        const f32x4 bv4 = *(const f32x4*)b;
        f32x4 o;
        o[0] = w0 * scale + (second ? 0.f : bv4[0]);
        o[1] = w1 * scale + (second ? 0.f : bv4[1]);
        o[2] = w2 * scale + (second ? 0.f : bv4[2]);
        o[3] = w3 * scale + (second ? 0.f : bv4[3]);

        if (!(nodeB && !has1))
            *(f32x4*)(y + (size_t)n0 * 8 + li * 4) = o;   // idempotent
    }
}

// 1 edge per thread, exact grid (R11, unchanged).
__global__ __launch_bounds__(256) void edge_kernel(
    const int* __restrict__ idx, const float* __restrict__ y,
    float* __restrict__ out, int n_edges)
{
    const int e = blockIdx.x * blockDim.x + threadIdx.x;
    if (e >= n_edges) return;
    const i32x2 ii = __builtin_nontemporal_load((const i32x2*)idx + e);
    const f32x4 a0 = *(const f32x4*)(y + (size_t)ii[0] * 8);
    const f32x4 c0 = *(const f32x4*)(y + (size_t)ii[1] * 8 + 4);
    const f32x4 o0 = a0 + c0;
    __builtin_nontemporal_store(o0, (f32x4*)out + e);
}

extern "C" void kernel_launch(void* const* d_in, const int* in_sizes, int n_in,
                              void* d_out, int out_size, void* d_ws, size_t ws_size,
                              hipStream_t stream) {
    const float* x   = (const float*)d_in[0];
    const int*   idx = (const int*)d_in[1];
    const float* W   = (const float*)d_in[2];
    const float* b   = (const float*)d_in[3];
    float* out = (float*)d_out;

    const int n_nodes = in_sizes[0] / DIM;
    const int n_edges = in_sizes[1] / 2;

    float* y = (float*)d_ws;  // n_nodes * 8 floats = 3.2 MB

    // Node: 32 nodes/wave, 4 waves/block, x5 diagnostic repeat.
    const int blocks1 = (n_nodes + 127) / 128;
    node_proj_kernel<<<blocks1, 256, 0, stream>>>(x, W, b, y, n_nodes,
                                                  NODE_REPEATS);

    // Edge: 1 edge/thread, exact grid (1M threads).
    const int blocks2 = (n_edges + 255) / 256;
    edge_kernel<<<blocks2, 256, 0, stream>>>(idx, y, out, n_edges);
}

// Round 13
// 30.500 us; speedup vs baseline: 2.0830x; 2.0830x over previous
//
#include <hip/hip_runtime.h>
#include <hip/hip_bf16.h>

// out[e] = concat(h[i0], h[i1]) @ W + b, h = logmap0(x)
// Rewritten: y[n][0:4] = h[n]·W[0:128,:] + b   (b folded here)
//            y[n][4:8] = h[n]·W[128:256,:]
//            out[e][c] = y[i0][c] + y[i1][4+c]
// Two dispatches (fusion measured WORSE, R10). R13: node uses 1 node per
// 4-lane group (16 nodes/wave) -> 6250 waves -> ~6 waves/SIMD, 2x the TLP
// of the 2-node version (R12 counters: latency-bound at 3 waves/SIMD,
// VALUBusy 25%, occupancy 21.6%).

#define DIM 128

typedef float f32x4 __attribute__((ext_vector_type(4)));
typedef int   i32x2 __attribute__((ext_vector_type(2)));

// Lane li of a group owns dims {j*16 + li*4 + k : j=0..7, k=0..3}.
// W packed in LDS: Wp[d] = {W[d][0:4], W[d+128][0:4]} at float-offset
// d*8 + (d>>2)*4 (skew every 4 rows -> 4 distinct banks-quads per read
// instruction; 16-lane broadcast per address; 0 conflicts measured).
__global__ __launch_bounds__(256) void node_proj_kernel(
    const float* __restrict__ x, const float* __restrict__ W,
    const float* __restrict__ b, float* __restrict__ y, int n_nodes)
{
    __shared__ float wp[1152];
    const int t = threadIdx.x;
    {
        const int r = t & 127, h = t >> 7;            // row, half
        const f32x4 wv = ((const f32x4*)W)[t];        // W[256][4], row t
        *(f32x4*)(wp + r * 8 + (r >> 2) * 4 + h * 4) = wv;
    }
    __syncthreads();

    const int lane = t & 63;
    const int li   = lane & 3;
    const int gid  = lane >> 2;
    const int wid  = blockIdx.x * (blockDim.x >> 6) + (t >> 6);
    const int n0   = wid * 16 + gid;            // 1 node per 4-lane group
    if (n0 >= n_nodes) return;

    const f32x4* xp0 = (const f32x4*)(x + (size_t)n0 * DIM + li * 4);
    const float* wl  = wp + li * 36;   // f(li*4) = li*32 + li*4

    float acc[9];
#pragma unroll
    for (int i = 0; i < 9; ++i) acc[i] = 0.f;

#pragma unroll
    for (int j = 0; j < 8; ++j) {
        const f32x4 a4 = xp0[j * 4];
#pragma unroll
        for (int k = 0; k < 4; ++k) {
            // d = j*16 + li*4 + k ; float-offset f(d) = li*36 + j*144 + k*8
            const f32x4 wa = *(const f32x4*)(wl + j * 144 + k * 8);
            const f32x4 wb = *(const f32x4*)(wl + j * 144 + k * 8 + 4);
            const float a = a4[k];
            acc[0] += a * a;
            acc[1] += a * wa[0];
            acc[2] += a * wa[1];
            acc[3] += a * wa[2];
            acc[4] += a * wa[3];
            acc[5] += a * wb[0];
            acc[6] += a * wb[1];
            acc[7] += a * wb[2];
            acc[8] += a * wb[3];
        }
    }

    // 2-step butterfly within each 4-lane group (xor 1,2 -> DPP quad_perm).
#pragma unroll
    for (int i = 0; i < 9; ++i) {
        acc[i] += __shfl_xor(acc[i], 1, 64);
        acc[i] += __shfl_xor(acc[i], 2, 64);
    }

    // li=0 writes y[n0][0:4] (+bias), li=1 writes y[n0][4:8]; li>=2 idle.
    if (li < 2) {
        const bool second = li;

        float norm = fmaxf(sqrtf(acc[0]), 1e-15f);           // MIN_NORM
        const float aa  = fminf(norm, 1.0f - 1e-6f);         // ATANH_EPS clip
        const float art = 0.5f * log1pf(2.0f * aa / (1.0f - aa));  // artanh
        const float scale = art / norm;

        const float w0 = second ? acc[5] : acc[1];
        const float w1 = second ? acc[6] : acc[2];
        const float w2 = second ? acc[7] : acc[3];
        const float w3 = second ? acc[8] : acc[4];

        const f32x4 bv4 = *(const f32x4*)b;
        f32x4 o;
        o[0] = w0 * scale + (second ? 0.f : bv4[0]);
        o[1] = w1 * scale + (second ? 0.f : bv4[1]);
        o[2] = w2 * scale + (second ? 0.f : bv4[2]);
        o[3] = w3 * scale + (second ? 0.f : bv4[3]);

        *(f32x4*)(y + (size_t)n0 * 8 + li * 4) = o;
    }
}

// 1 edge per thread, exact grid: maximum outstanding gathers (R10 lesson:
// gathers are latency-bound -> TLP is the lever). idx/out nontemporal
// (streaming; keeps the 3.2 MB y table L2-resident); y gathers plain.
__global__ __launch_bounds__(256) void edge_kernel(
    const int* __restrict__ idx, const float* __restrict__ y,
    float* __restrict__ out, int n_edges)
{
    const int e = blockIdx.x * blockDim.x + threadIdx.x;
    if (e >= n_edges) return;
    const i32x2 ii = __builtin_nontemporal_load((const i32x2*)idx + e);
    const f32x4 a0 = *(const f32x4*)(y + (size_t)ii[0] * 8);
    const f32x4 c0 = *(const f32x4*)(y + (size_t)ii[1] * 8 + 4);
    const f32x4 o0 = a0 + c0;
    __builtin_nontemporal_store(o0, (f32x4*)out + e);
}

extern "C" void kernel_launch(void* const* d_in, const int* in_sizes, int n_in,
                              void* d_out, int out_size, void* d_ws, size_t ws_size,
                              hipStream_t stream) {
    const float* x   = (const float*)d_in[0];
    const int*   idx = (const int*)d_in[1];
    const float* W   = (const float*)d_in[2];
    const float* b   = (const float*)d_in[3];
    float* out = (float*)d_out;

    const int n_nodes = in_sizes[0] / DIM;
    const int n_edges = in_sizes[1] / 2;

    float* y = (float*)d_ws;  // n_nodes * 8 floats = 3.2 MB

    // Node: 16 nodes/wave, 4 waves/block -> 64 nodes/block, single-shot.
    // 1563 blocks ~ 6 blocks/CU -> ~6 waves/SIMD (2x R12's TLP).
    const int blocks1 = (n_nodes + 63) / 64;
    node_proj_kernel<<<blocks1, 256, 0, stream>>>(x, W, b, y, n_nodes);

    // Edge: 1 edge/thread, exact grid (1M threads).
    const int blocks2 = (n_edges + 255) / 256;
    edge_kernel<<<blocks2, 256, 0, stream>>>(idx, y, out, n_edges);
}